// Round 9
// baseline (642.952 us; speedup 1.0000x reference)
//
#include <hip/hip_runtime.h>
#include <hip/hip_bf16.h>

// GraphSAGE 3-layer, N=100000, E=1.6M, dims 256->256->128->1.
// R9: collapse the serial per-layer chain via row-wise fusion:
//  (a) agg256 + L2 GEMM in one kernel (agg 64 nodes -> LDS tile -> MFMA),
//      killing the X2b HBM roundtrip;
//  (b) agg128 + gemv_l3 in registers (half-wave holds h2 lane-distributed),
//      killing X3b entirely.
// gemm_l1_fill overlap (R8: 268->142us) kept as-is.

typedef __attribute__((ext_vector_type(8))) short short8;
typedef __attribute__((ext_vector_type(4))) float f32x4;

__device__ __forceinline__ unsigned short f2b(float f) {
    __hip_bfloat16 h = __float2bfloat16(f);
    return *reinterpret_cast<unsigned short*>(&h);
}
__device__ __forceinline__ float b2f(unsigned short u) {
    union { unsigned int i; float f; } v; v.i = ((unsigned int)u) << 16; return v.f;
}

// ---- fused prep: convert_x | prep_w x4 | count_deg ----------------------
__global__ __launch_bounds__(256) void prep_fused(
    const float* __restrict__ x, unsigned short* __restrict__ xb,
    const float* __restrict__ Wl1, const float* __restrict__ Wr1,
    const float* __restrict__ Wl2, const float* __restrict__ Wr2,
    unsigned short* __restrict__ Wl1s, unsigned short* __restrict__ Wr1s,
    unsigned short* __restrict__ Wl2s, unsigned short* __restrict__ Wr2s,
    const int* __restrict__ dst, int* __restrict__ deg, int E)
{
    const int b = blockIdx.x;
    const int tid = threadIdx.x;
    if (b < 25000) {
        const int i = b * 256 + tid;
        float4 v = *(const float4*)(x + (size_t)i * 4);
        ushort4 o;
        o.x = f2b(v.x); o.y = f2b(v.y); o.z = f2b(v.z); o.w = f2b(v.w);
        *(ushort4*)(xb + (size_t)i * 4) = o;
    } else if (b < 25768) {
        const float* W; unsigned short* O; int base, hs;
        if (b < 25256)      { W = Wl1; O = Wl1s; base = b - 25000; hs = 8; }
        else if (b < 25512) { W = Wr1; O = Wr1s; base = b - 25256; hs = 8; }
        else if (b < 25640) { W = Wl2; O = Wl2s; base = b - 25512; hs = 7; }
        else                { W = Wr2; O = Wr2s; base = b - 25640; hs = 7; }
        const int i = base * 256 + tid;
        const int k = i >> hs;
        const int h = i & ((1 << hs) - 1);
        O[((size_t)(((k >> 3) << hs) + h) << 3) + (k & 7)] = f2b(W[i]);
    } else {
        const int e = (b - 25768) * 256 + tid;
        if (e < E) atomicAdd(&deg[dst[e]], 1);
    }
}

// ---- scan ----------------------------------------------------------------
__global__ __launch_bounds__(256) void scan_phaseA(int* __restrict__ a,
                                                   int* __restrict__ blockSums, int n) {
    __shared__ int sh[256];
    const int tid = threadIdx.x;
    const int base = blockIdx.x * 1024 + tid * 4;
    int v[4];
    #pragma unroll
    for (int i = 0; i < 4; ++i) v[i] = (base + i < n) ? a[base + i] : 0;
    int tsum = v[0] + v[1] + v[2] + v[3];
    sh[tid] = tsum;
    __syncthreads();
    for (int off = 1; off < 256; off <<= 1) {
        int t = (tid >= off) ? sh[tid - off] : 0;
        __syncthreads();
        sh[tid] += t;
        __syncthreads();
    }
    int run = sh[tid] - tsum;
    #pragma unroll
    for (int i = 0; i < 4; ++i) {
        if (base + i < n) a[base + i] = run;
        run += v[i];
    }
    if (tid == 255) blockSums[blockIdx.x] = sh[255];
}

__global__ __launch_bounds__(256) void scan_phaseB(int* __restrict__ bs, int nb) {
    __shared__ int sh[256];
    const int tid = threadIdx.x;
    int v = (tid < nb) ? bs[tid] : 0;
    sh[tid] = v;
    __syncthreads();
    for (int off = 1; off < 256; off <<= 1) {
        int t = (tid >= off) ? sh[tid - off] : 0;
        __syncthreads();
        sh[tid] += t;
        __syncthreads();
    }
    if (tid < nb) bs[tid] = sh[tid] - v;
}

__global__ __launch_bounds__(256) void scan_phaseC(int* __restrict__ a,
                                                   const int* __restrict__ bs, int n) {
    const int base = blockIdx.x * 1024 + threadIdx.x * 4;
    const int add = bs[blockIdx.x];
    #pragma unroll
    for (int i = 0; i < 4; ++i)
        if (base + i < n) a[base + i] += add;
}

// ---- fused L1 GEMM + fill_csr (1 gemm : 2 fill interleave) ---------------
__global__ __launch_bounds__(256) void gemm_l1_fill(
    const unsigned short* __restrict__ Xb,
    const unsigned short* __restrict__ Wsw_l,
    const unsigned short* __restrict__ Wsw_r,
    const float* __restrict__ bias,
    unsigned short* __restrict__ Tout,
    unsigned short* __restrict__ Abase,
    int M,
    const int* __restrict__ src, const int* __restrict__ dst,
    int* __restrict__ cursor, int* __restrict__ csr, int E)
{
    const int grp = blockIdx.x / 3;
    const int rem = blockIdx.x - grp * 3;
    const int tid = threadIdx.x;

    if (rem != 0) {                        // fill_csr part
        const int e = (grp * 2 + rem - 1) * 256 + tid;
        if (e < E) {
            int p = atomicAdd(&cursor[dst[e]], 1);
            csr[p] = src[e];
        }
        return;
    }

    // gemm part (H = 256)
    const int H = 256;
    const int wid = tid >> 6;
    const int lane = tid & 63;
    const int quad = lane >> 4;
    const int l15 = lane & 15;
    const int col0 = (grp & 3) << 6;
    const int m0 = (grp >> 2) * 128 + wid * 32;

    const unsigned short* aptr[2];
    #pragma unroll
    for (int mt = 0; mt < 2; ++mt) {
        int r = m0 + mt * 16 + l15;
        if (r > M - 1) r = M - 1;
        aptr[mt] = Xb + ((size_t)r << 8) + (quad << 3);
    }
    const unsigned short* bptr[8];   // 0..3 = Wl, 4..7 = Wr
    #pragma unroll
    for (int nt = 0; nt < 4; ++nt) {
        const int col = col0 + nt * 16 + l15;
        bptr[nt]     = Wsw_l + (((size_t)quad * H + col) << 3);
        bptr[nt + 4] = Wsw_r + (((size_t)quad * H + col) << 3);
    }

    const f32x4 zero = {0.f, 0.f, 0.f, 0.f};
    f32x4 acc[2][8];
    #pragma unroll
    for (int mt = 0; mt < 2; ++mt)
        #pragma unroll
        for (int nt = 0; nt < 8; ++nt) acc[mt][nt] = zero;

    #pragma unroll 2
    for (int ks = 0; ks < 8; ++ks) {
        short8 af[2], bf[8];
        #pragma unroll
        for (int mt = 0; mt < 2; ++mt)
            af[mt] = *(const short8*)(aptr[mt] + ks * 32);
        #pragma unroll
        for (int nt = 0; nt < 8; ++nt)
            bf[nt] = *(const short8*)(bptr[nt] + (size_t)ks * 32 * H);
        #pragma unroll
        for (int mt = 0; mt < 2; ++mt)
            #pragma unroll
            for (int nt = 0; nt < 8; ++nt)
                acc[mt][nt] = __builtin_amdgcn_mfma_f32_16x16x32_bf16(
                    af[mt], bf[nt], acc[mt][nt], 0, 0, 0);
    }

    #pragma unroll
    for (int nt = 0; nt < 4; ++nt) {
        const int colg = col0 + nt * 16 + l15;
        const float bb = bias[colg];
        #pragma unroll
        for (int mt = 0; mt < 2; ++mt) {
            const int gmb = m0 + mt * 16 + quad * 4;
            #pragma unroll
            for (int r = 0; r < 4; ++r) {
                if (gmb + r < M) {
                    Tout [(size_t)(gmb + r) * H + colg] = f2b(acc[mt][nt][r]);
                    Abase[(size_t)(gmb + r) * H + colg] = f2b(acc[mt][nt + 4][r] + bb);
                }
            }
        }
    }
}

// ---- fused layer-2: agg256 (-> LDS tile) + GEMM --------------------------
// Block = 64 nodes. Phase1: 4 waves x 16 nodes gather-mean T1 rows (512B),
// add base, relu -> LDS [64][264] bf16 (pad 8 shorts: bank-uniform b128).
// Phase2: two passes (Wl2 -> T2b, Wr2+bias -> A2b); wave w = rows w*16..+15,
// cols 0..127, K=256.
__global__ __launch_bounds__(256) void agg_gemm2(
    const int* __restrict__ endoff, const int* __restrict__ csr,
    const unsigned short* __restrict__ T, const unsigned short* __restrict__ Ab,
    const unsigned short* __restrict__ Wsw_l, const unsigned short* __restrict__ Wsw_r,
    const float* __restrict__ bias,
    unsigned short* __restrict__ Tout, unsigned short* __restrict__ Aout, int N)
{
    __shared__ unsigned short Xs[64 * 264];   // 33 KB
    const int tid = threadIdx.x;
    const int wid = tid >> 6;
    const int lane = tid & 63;
    const int nb = blockIdx.x * 64;

    // ---- phase 1: aggregate 16 nodes per wave ----
    for (int i = 0; i < 16; ++i) {
        const int row = wid * 16 + i;
        const int node = nb + row;
        ushort4 o = make_ushort4(0, 0, 0, 0);
        if (node < N) {
            const int end = endoff[node];
            const int beg = node ? endoff[node - 1] : 0;
            float s0 = 0.f, s1 = 0.f, s2 = 0.f, s3 = 0.f;
            int p = beg;
            for (; p + 4 <= end; p += 4) {
                const int a = csr[p], b = csr[p + 1], c = csr[p + 2], d = csr[p + 3];
                ushort4 v0 = *(const ushort4*)(T + ((size_t)a << 8) + (lane << 2));
                ushort4 v1 = *(const ushort4*)(T + ((size_t)b << 8) + (lane << 2));
                ushort4 v2 = *(const ushort4*)(T + ((size_t)c << 8) + (lane << 2));
                ushort4 v3 = *(const ushort4*)(T + ((size_t)d << 8) + (lane << 2));
                s0 += (b2f(v0.x) + b2f(v1.x)) + (b2f(v2.x) + b2f(v3.x));
                s1 += (b2f(v0.y) + b2f(v1.y)) + (b2f(v2.y) + b2f(v3.y));
                s2 += (b2f(v0.z) + b2f(v1.z)) + (b2f(v2.z) + b2f(v3.z));
                s3 += (b2f(v0.w) + b2f(v1.w)) + (b2f(v2.w) + b2f(v3.w));
            }
            for (; p < end; ++p) {
                ushort4 v = *(const ushort4*)(T + ((size_t)csr[p] << 8) + (lane << 2));
                s0 += b2f(v.x); s1 += b2f(v.y); s2 += b2f(v.z); s3 += b2f(v.w);
            }
            const float w = 1.0f / fmaxf((float)(end - beg), 1.0f);
            const ushort4 bu = *(const ushort4*)(Ab + ((size_t)node << 8) + (lane << 2));
            o.x = f2b(fmaxf(b2f(bu.x) + s0 * w, 0.f));
            o.y = f2b(fmaxf(b2f(bu.y) + s1 * w, 0.f));
            o.z = f2b(fmaxf(b2f(bu.z) + s2 * w, 0.f));
            o.w = f2b(fmaxf(b2f(bu.w) + s3 * w, 0.f));
        }
        *(ushort4*)(&Xs[row * 264 + (lane << 2)]) = o;
    }
    __syncthreads();

    // ---- phase 2: GEMM from LDS, H=128, two passes ----
    const int H = 128;
    const int quad = lane >> 4;
    const int l15 = lane & 15;
    const int arow = wid * 16 + l15;

    #pragma unroll
    for (int pass = 0; pass < 2; ++pass) {
        const unsigned short* Wsw = pass ? Wsw_r : Wsw_l;
        const f32x4 zero = {0.f, 0.f, 0.f, 0.f};
        f32x4 acc[8];
        #pragma unroll
        for (int nt = 0; nt < 8; ++nt) acc[nt] = zero;

        #pragma unroll 2
        for (int ks = 0; ks < 8; ++ks) {
            const short8 a = *(const short8*)(&Xs[arow * 264 + ks * 32 + quad * 8]);
            #pragma unroll
            for (int nt = 0; nt < 8; ++nt) {
                const int col = nt * 16 + l15;
                const short8 bf = *(const short8*)(
                    Wsw + (((size_t)(ks * 4 + quad) * H + col) << 3));
                acc[nt] = __builtin_amdgcn_mfma_f32_16x16x32_bf16(a, bf, acc[nt], 0, 0, 0);
            }
        }

        unsigned short* O = pass ? Aout : Tout;
        #pragma unroll
        for (int nt = 0; nt < 8; ++nt) {
            const int colg = nt * 16 + l15;
            const float bb = pass ? bias[colg] : 0.f;
            const int gmb = nb + wid * 16 + quad * 4;
            #pragma unroll
            for (int r = 0; r < 4; ++r)
                if (gmb + r < N)
                    O[(size_t)(gmb + r) * H + colg] = f2b(acc[nt][r] + bb);
        }
    }
}

// ---- fused layer-3: agg128 + gemv (register-resident h2) -----------------
// Half-wave (32 lanes) per node: gather-mean T2 rows, add base, relu (fp32),
// dot with Wl3/Wr3 in registers, half-wave shuffle reduce.
__global__ __launch_bounds__(256) void agg_gemv3(
    const int* __restrict__ endoff, const int* __restrict__ csr,
    const unsigned short* __restrict__ T, const unsigned short* __restrict__ Ab,
    const float* __restrict__ Wl, const float* __restrict__ Wr,
    const float* __restrict__ b,
    float* __restrict__ t3, float* __restrict__ out, int N)
{
    const int node = (int)((blockIdx.x * 256 + threadIdx.x) >> 5);
    const int lane = threadIdx.x & 31;
    if (node >= N) return;
    const int end = endoff[node];
    const int beg = node ? endoff[node - 1] : 0;
    float s0 = 0.f, s1 = 0.f, s2 = 0.f, s3 = 0.f;
    int p = beg;
    for (; p + 4 <= end; p += 4) {
        const int a = csr[p], bb = csr[p + 1], c = csr[p + 2], d = csr[p + 3];
        ushort4 v0 = *(const ushort4*)(T + ((size_t)a << 7) + (lane << 2));
        ushort4 v1 = *(const ushort4*)(T + ((size_t)bb << 7) + (lane << 2));
        ushort4 v2 = *(const ushort4*)(T + ((size_t)c << 7) + (lane << 2));
        ushort4 v3 = *(const ushort4*)(T + ((size_t)d << 7) + (lane << 2));
        s0 += (b2f(v0.x) + b2f(v1.x)) + (b2f(v2.x) + b2f(v3.x));
        s1 += (b2f(v0.y) + b2f(v1.y)) + (b2f(v2.y) + b2f(v3.y));
        s2 += (b2f(v0.z) + b2f(v1.z)) + (b2f(v2.z) + b2f(v3.z));
        s3 += (b2f(v0.w) + b2f(v1.w)) + (b2f(v2.w) + b2f(v3.w));
    }
    for (; p < end; ++p) {
        ushort4 v = *(const ushort4*)(T + ((size_t)csr[p] << 7) + (lane << 2));
        s0 += b2f(v.x); s1 += b2f(v.y); s2 += b2f(v.z); s3 += b2f(v.w);
    }
    const float w = 1.0f / fmaxf((float)(end - beg), 1.0f);
    const ushort4 bu = *(const ushort4*)(Ab + ((size_t)node << 7) + (lane << 2));
    const float h0 = fmaxf(b2f(bu.x) + s0 * w, 0.f);
    const float h1 = fmaxf(b2f(bu.y) + s1 * w, 0.f);
    const float h2 = fmaxf(b2f(bu.z) + s2 * w, 0.f);
    const float h3 = fmaxf(b2f(bu.w) + s3 * w, 0.f);

    const float4 wl = *(const float4*)(Wl + (lane << 2));
    const float4 wr = *(const float4*)(Wr + (lane << 2));
    float dl = h0 * wl.x + h1 * wl.y + h2 * wl.z + h3 * wl.w;
    float dr = h0 * wr.x + h1 * wr.y + h2 * wr.z + h3 * wr.w;
    #pragma unroll
    for (int off = 16; off > 0; off >>= 1) {
        dl += __shfl_down(dl, off, 64);
        dr += __shfl_down(dr, off, 64);
    }
    if (lane == 0) {
        t3[node] = dl;
        out[node] = dr + b[0];
    }
}

__global__ __launch_bounds__(256) void agg1(
    const int* __restrict__ endoff, const int* __restrict__ csr,
    const float* __restrict__ t3, float* __restrict__ out, int N)
{
    const int i = blockIdx.x * blockDim.x + threadIdx.x;
    if (i >= N) return;
    const int end = endoff[i];
    const int beg = i ? endoff[i - 1] : 0;
    int p = beg;
    float s = 0.f;
    for (; p + 4 <= end; p += 4)
        s += (t3[csr[p]] + t3[csr[p + 1]]) + (t3[csr[p + 2]] + t3[csr[p + 3]]);
    for (; p < end; ++p) s += t3[csr[p]];
    out[i] += s / fmaxf((float)(end - beg), 1.0f);
}

extern "C" void kernel_launch(void* const* d_in, const int* in_sizes, int n_in,
                              void* d_out, int out_size, void* d_ws, size_t ws_size,
                              hipStream_t stream) {
    const float* x   = (const float*)d_in[0];
    const int*   ei  = (const int*)d_in[1];
    const float* Wl1 = (const float*)d_in[2];
    const float* bl1 = (const float*)d_in[3];
    const float* Wr1 = (const float*)d_in[4];
    const float* Wl2 = (const float*)d_in[5];
    const float* bl2 = (const float*)d_in[6];
    const float* Wr2 = (const float*)d_in[7];
    const float* Wl3 = (const float*)d_in[8];
    const float* bl3 = (const float*)d_in[9];
    const float* Wr3 = (const float*)d_in[10];
    float* out = (float*)d_out;

    const int N = in_sizes[0] / 256;   // 100000
    const int E = in_sizes[1] / 2;     // 1600000
    const int* src = ei;
    const int* dst = ei + E;

    // ---- workspace layout, race-free aliasing ----------------------------
    //   prep:       W X1b[0,51.2)
    //   L1+fill:    R X1b               W T1b[51.2,102.4) A1b[102.4,153.6) csr
    //   agg_gemm2:  R T1b,A1b,csr       W T2b[0,25.6) A2b[25.6,51.2)  (X1b dead)
    //   agg_gemv3:  R T2b,A2b,csr       W t3,out
    //   agg1:       R t3,csr            RW out
    char* W = (char*)d_ws;
    const size_t MB512 = (size_t)100000 * 512;   // 51.2MB
    unsigned short* X1b = (unsigned short*)(W);
    unsigned short* T1b = (unsigned short*)(W + MB512);
    unsigned short* A1b = (unsigned short*)(W + 2 * MB512);
    unsigned short* T2b = (unsigned short*)(W);                  // over dead X1b
    unsigned short* A2b = (unsigned short*)(W + MB512 / 2);
    char* S = W + 3 * MB512;                     // smalls @ 153.6M
    int*   endoff = (int*)(S);
    int*   bsums  = (int*)(S + (size_t)N * 4);
    float* t3     = (float*)(S + (size_t)N * 4 + 1024);
    int*   csr    = (int*)(S + (size_t)N * 8 + 1024);
    unsigned short* Wl1s = (unsigned short*)(S + (size_t)N * 8 + 1024 + (size_t)E * 4);
    unsigned short* Wr1s = Wl1s + 65536;
    unsigned short* Wl2s = Wr1s + 65536;
    unsigned short* Wr2s = Wl2s + 32768;

    // ---- prep: fused conversions + degree count ----
    hipMemsetAsync(endoff, 0, (size_t)N * sizeof(int), stream);
    prep_fused<<<32018, 256, 0, stream>>>(x, X1b, Wl1, Wr1, Wl2, Wr2,
                                          Wl1s, Wr1s, Wl2s, Wr2s,
                                          dst, endoff, E);
    const int nScanBlocks = (N + 1023) / 1024;
    scan_phaseA<<<nScanBlocks, 256, 0, stream>>>(endoff, bsums, N);
    scan_phaseB<<<1, 256, 0, stream>>>(bsums, nScanBlocks);
    scan_phaseC<<<nScanBlocks, 256, 0, stream>>>(endoff, bsums, N);

    // ---- Layer 1 GEMM fused with fill_csr ----
    gemm_l1_fill<<<3128 * 3, 256, 0, stream>>>(X1b, Wl1s, Wr1s, bl1, T1b, A1b, N,
                                               src, dst, endoff, csr, E);

    // ---- Layer 2: fused agg256 + GEMM ----
    agg_gemm2<<<(N + 63) / 64, 256, 0, stream>>>(endoff, csr, T1b, A1b,
                                                 Wl2s, Wr2s, bl2, T2b, A2b, N);

    // ---- Layer 3: fused agg128 + gemv, then final scalar aggregation ----
    agg_gemv3<<<(N * 32 + 255) / 256, 256, 0, stream>>>(endoff, csr, T2b, A2b,
                                                        Wl3, Wr3, bl3, t3, out, N);
    agg1<<<(N + 255) / 256, 256, 0, stream>>>(endoff, csr, t3, out, N);
}

// Round 10
// 619.591 us; speedup vs baseline: 1.0377x; 1.0377x over previous
//
#include <hip/hip_runtime.h>
#include <hip/hip_bf16.h>

// GraphSAGE 3-layer, N=100000, E=1.6M, dims 256->256->128->1.
// R10: revert R9's agg+gemm fusion (204us, latency-bound at 34% occupancy,
// 16-node sequential gather per wave) back to R8's split (one-wave-per-node
// gather TLP). agg256_b upgraded to half-wave x 16B loads (2 gather streams
// per wave, 8 loads in flight). Keep agg_gemv3 fusion + gemm_l1_fill overlap.

typedef __attribute__((ext_vector_type(8))) short short8;
typedef __attribute__((ext_vector_type(4))) float f32x4;

__device__ __forceinline__ unsigned short f2b(float f) {
    __hip_bfloat16 h = __float2bfloat16(f);
    return *reinterpret_cast<unsigned short*>(&h);
}
__device__ __forceinline__ float b2f(unsigned short u) {
    union { unsigned int i; float f; } v; v.i = ((unsigned int)u) << 16; return v.f;
}

// ---- fused prep: convert_x | prep_w x4 | count_deg ----------------------
__global__ __launch_bounds__(256) void prep_fused(
    const float* __restrict__ x, unsigned short* __restrict__ xb,
    const float* __restrict__ Wl1, const float* __restrict__ Wr1,
    const float* __restrict__ Wl2, const float* __restrict__ Wr2,
    unsigned short* __restrict__ Wl1s, unsigned short* __restrict__ Wr1s,
    unsigned short* __restrict__ Wl2s, unsigned short* __restrict__ Wr2s,
    const int* __restrict__ dst, int* __restrict__ deg, int E)
{
    const int b = blockIdx.x;
    const int tid = threadIdx.x;
    if (b < 25000) {
        const int i = b * 256 + tid;
        float4 v = *(const float4*)(x + (size_t)i * 4);
        ushort4 o;
        o.x = f2b(v.x); o.y = f2b(v.y); o.z = f2b(v.z); o.w = f2b(v.w);
        *(ushort4*)(xb + (size_t)i * 4) = o;
    } else if (b < 25768) {
        const float* W; unsigned short* O; int base, hs;
        if (b < 25256)      { W = Wl1; O = Wl1s; base = b - 25000; hs = 8; }
        else if (b < 25512) { W = Wr1; O = Wr1s; base = b - 25256; hs = 8; }
        else if (b < 25640) { W = Wl2; O = Wl2s; base = b - 25512; hs = 7; }
        else                { W = Wr2; O = Wr2s; base = b - 25640; hs = 7; }
        const int i = base * 256 + tid;
        const int k = i >> hs;
        const int h = i & ((1 << hs) - 1);
        O[((size_t)(((k >> 3) << hs) + h) << 3) + (k & 7)] = f2b(W[i]);
    } else {
        const int e = (b - 25768) * 256 + tid;
        if (e < E) atomicAdd(&deg[dst[e]], 1);
    }
}

// ---- scan ----------------------------------------------------------------
__global__ __launch_bounds__(256) void scan_phaseA(int* __restrict__ a,
                                                   int* __restrict__ blockSums, int n) {
    __shared__ int sh[256];
    const int tid = threadIdx.x;
    const int base = blockIdx.x * 1024 + tid * 4;
    int v[4];
    #pragma unroll
    for (int i = 0; i < 4; ++i) v[i] = (base + i < n) ? a[base + i] : 0;
    int tsum = v[0] + v[1] + v[2] + v[3];
    sh[tid] = tsum;
    __syncthreads();
    for (int off = 1; off < 256; off <<= 1) {
        int t = (tid >= off) ? sh[tid - off] : 0;
        __syncthreads();
        sh[tid] += t;
        __syncthreads();
    }
    int run = sh[tid] - tsum;
    #pragma unroll
    for (int i = 0; i < 4; ++i) {
        if (base + i < n) a[base + i] = run;
        run += v[i];
    }
    if (tid == 255) blockSums[blockIdx.x] = sh[255];
}

__global__ __launch_bounds__(256) void scan_phaseB(int* __restrict__ bs, int nb) {
    __shared__ int sh[256];
    const int tid = threadIdx.x;
    int v = (tid < nb) ? bs[tid] : 0;
    sh[tid] = v;
    __syncthreads();
    for (int off = 1; off < 256; off <<= 1) {
        int t = (tid >= off) ? sh[tid - off] : 0;
        __syncthreads();
        sh[tid] += t;
        __syncthreads();
    }
    if (tid < nb) bs[tid] = sh[tid] - v;
}

__global__ __launch_bounds__(256) void scan_phaseC(int* __restrict__ a,
                                                   const int* __restrict__ bs, int n) {
    const int base = blockIdx.x * 1024 + threadIdx.x * 4;
    const int add = bs[blockIdx.x];
    #pragma unroll
    for (int i = 0; i < 4; ++i)
        if (base + i < n) a[base + i] += add;
}

// ---- fused L1 GEMM + fill_csr (1 gemm : 2 fill interleave) ---------------
__global__ __launch_bounds__(256) void gemm_l1_fill(
    const unsigned short* __restrict__ Xb,
    const unsigned short* __restrict__ Wsw_l,
    const unsigned short* __restrict__ Wsw_r,
    const float* __restrict__ bias,
    unsigned short* __restrict__ Tout,
    unsigned short* __restrict__ Abase,
    int M,
    const int* __restrict__ src, const int* __restrict__ dst,
    int* __restrict__ cursor, int* __restrict__ csr, int E)
{
    const int grp = blockIdx.x / 3;
    const int rem = blockIdx.x - grp * 3;
    const int tid = threadIdx.x;

    if (rem != 0) {                        // fill_csr part
        const int e = (grp * 2 + rem - 1) * 256 + tid;
        if (e < E) {
            int p = atomicAdd(&cursor[dst[e]], 1);
            csr[p] = src[e];
        }
        return;
    }

    // gemm part (H = 256)
    const int H = 256;
    const int wid = tid >> 6;
    const int lane = tid & 63;
    const int quad = lane >> 4;
    const int l15 = lane & 15;
    const int col0 = (grp & 3) << 6;
    const int m0 = (grp >> 2) * 128 + wid * 32;

    const unsigned short* aptr[2];
    #pragma unroll
    for (int mt = 0; mt < 2; ++mt) {
        int r = m0 + mt * 16 + l15;
        if (r > M - 1) r = M - 1;
        aptr[mt] = Xb + ((size_t)r << 8) + (quad << 3);
    }
    const unsigned short* bptr[8];   // 0..3 = Wl, 4..7 = Wr
    #pragma unroll
    for (int nt = 0; nt < 4; ++nt) {
        const int col = col0 + nt * 16 + l15;
        bptr[nt]     = Wsw_l + (((size_t)quad * H + col) << 3);
        bptr[nt + 4] = Wsw_r + (((size_t)quad * H + col) << 3);
    }

    const f32x4 zero = {0.f, 0.f, 0.f, 0.f};
    f32x4 acc[2][8];
    #pragma unroll
    for (int mt = 0; mt < 2; ++mt)
        #pragma unroll
        for (int nt = 0; nt < 8; ++nt) acc[mt][nt] = zero;

    #pragma unroll 2
    for (int ks = 0; ks < 8; ++ks) {
        short8 af[2], bf[8];
        #pragma unroll
        for (int mt = 0; mt < 2; ++mt)
            af[mt] = *(const short8*)(aptr[mt] + ks * 32);
        #pragma unroll
        for (int nt = 0; nt < 8; ++nt)
            bf[nt] = *(const short8*)(bptr[nt] + (size_t)ks * 32 * H);
        #pragma unroll
        for (int mt = 0; mt < 2; ++mt)
            #pragma unroll
            for (int nt = 0; nt < 8; ++nt)
                acc[mt][nt] = __builtin_amdgcn_mfma_f32_16x16x32_bf16(
                    af[mt], bf[nt], acc[mt][nt], 0, 0, 0);
    }

    #pragma unroll
    for (int nt = 0; nt < 4; ++nt) {
        const int colg = col0 + nt * 16 + l15;
        const float bb = bias[colg];
        #pragma unroll
        for (int mt = 0; mt < 2; ++mt) {
            const int gmb = m0 + mt * 16 + quad * 4;
            #pragma unroll
            for (int r = 0; r < 4; ++r) {
                if (gmb + r < M) {
                    Tout [(size_t)(gmb + r) * H + colg] = f2b(acc[mt][nt][r]);
                    Abase[(size_t)(gmb + r) * H + colg] = f2b(acc[mt][nt + 4][r] + bb);
                }
            }
        }
    }
}

// ---- layer-2 aggregation: half-wave per node, 16B/lane loads -------------
// node row = 256 bf16 = 512B = 32 lanes x ushort8. Two independent gather
// streams per wave; edge loop unrolled x4 -> 8 loads in flight.
__global__ __launch_bounds__(256) void agg256_b(
    const int* __restrict__ endoff, const int* __restrict__ csr,
    const unsigned short* __restrict__ T,
    const unsigned short* __restrict__ Abase, unsigned short* __restrict__ Xout, int N)
{
    const int node = (int)((blockIdx.x * 256 + threadIdx.x) >> 5);
    const int lane = threadIdx.x & 31;
    if (node >= N) return;
    const int end = endoff[node];
    const int beg = node ? endoff[node - 1] : 0;
    float s[8] = {0.f, 0.f, 0.f, 0.f, 0.f, 0.f, 0.f, 0.f};
    int p = beg;
    for (; p + 4 <= end; p += 4) {
        const int a = csr[p], b = csr[p + 1], c = csr[p + 2], d = csr[p + 3];
        const short8 v0 = *(const short8*)(T + ((size_t)a << 8) + (lane << 3));
        const short8 v1 = *(const short8*)(T + ((size_t)b << 8) + (lane << 3));
        const short8 v2 = *(const short8*)(T + ((size_t)c << 8) + (lane << 3));
        const short8 v3 = *(const short8*)(T + ((size_t)d << 8) + (lane << 3));
        #pragma unroll
        for (int j = 0; j < 8; ++j)
            s[j] += (b2f((unsigned short)v0[j]) + b2f((unsigned short)v1[j]))
                  + (b2f((unsigned short)v2[j]) + b2f((unsigned short)v3[j]));
    }
    for (; p < end; ++p) {
        const short8 v = *(const short8*)(T + ((size_t)csr[p] << 8) + (lane << 3));
        #pragma unroll
        for (int j = 0; j < 8; ++j) s[j] += b2f((unsigned short)v[j]);
    }
    const float w = 1.0f / fmaxf((float)(end - beg), 1.0f);
    const short8 bu = *(const short8*)(Abase + ((size_t)node << 8) + (lane << 3));
    short8 o;
    #pragma unroll
    for (int j = 0; j < 8; ++j)
        o[j] = (short)f2b(fmaxf(b2f((unsigned short)bu[j]) + s[j] * w, 0.f));
    *(short8*)(Xout + ((size_t)node << 8) + (lane << 3)) = o;
}

// ---- standalone L2 GEMM (H=128, K=256) -----------------------------------
__global__ __launch_bounds__(256) void gemm_bf16(
    const unsigned short* __restrict__ Xb,
    const unsigned short* __restrict__ Wsw_l,
    const unsigned short* __restrict__ Wsw_r,
    const float* __restrict__ bias,
    unsigned short* __restrict__ Tout,
    unsigned short* __restrict__ Abase,
    int M, int H)
{
    const int tid = threadIdx.x;
    const int wid = tid >> 6;
    const int lane = tid & 63;
    const int quad = lane >> 4;
    const int l15 = lane & 15;

    const int col0 = blockIdx.x << 6;
    const int m0 = blockIdx.y * 128 + wid * 32;

    const unsigned short* aptr[2];
    #pragma unroll
    for (int mt = 0; mt < 2; ++mt) {
        int r = m0 + mt * 16 + l15;
        if (r > M - 1) r = M - 1;
        aptr[mt] = Xb + ((size_t)r << 8) + (quad << 3);
    }
    const unsigned short* bptr[8];
    #pragma unroll
    for (int nt = 0; nt < 4; ++nt) {
        const int col = col0 + nt * 16 + l15;
        bptr[nt]     = Wsw_l + (((size_t)quad * H + col) << 3);
        bptr[nt + 4] = Wsw_r + (((size_t)quad * H + col) << 3);
    }

    const f32x4 zero = {0.f, 0.f, 0.f, 0.f};
    f32x4 acc[2][8];
    #pragma unroll
    for (int mt = 0; mt < 2; ++mt)
        #pragma unroll
        for (int nt = 0; nt < 8; ++nt) acc[mt][nt] = zero;

    #pragma unroll 2
    for (int ks = 0; ks < 8; ++ks) {
        short8 af[2], bf[8];
        #pragma unroll
        for (int mt = 0; mt < 2; ++mt)
            af[mt] = *(const short8*)(aptr[mt] + ks * 32);
        #pragma unroll
        for (int nt = 0; nt < 8; ++nt)
            bf[nt] = *(const short8*)(bptr[nt] + (size_t)ks * 32 * H);
        #pragma unroll
        for (int mt = 0; mt < 2; ++mt)
            #pragma unroll
            for (int nt = 0; nt < 8; ++nt)
                acc[mt][nt] = __builtin_amdgcn_mfma_f32_16x16x32_bf16(
                    af[mt], bf[nt], acc[mt][nt], 0, 0, 0);
    }

    #pragma unroll
    for (int nt = 0; nt < 4; ++nt) {
        const int colg = col0 + nt * 16 + l15;
        const float bb = bias[colg];
        #pragma unroll
        for (int mt = 0; mt < 2; ++mt) {
            const int gmb = m0 + mt * 16 + quad * 4;
            #pragma unroll
            for (int r = 0; r < 4; ++r) {
                if (gmb + r < M) {
                    Tout [(size_t)(gmb + r) * H + colg] = f2b(acc[mt][nt][r]);
                    Abase[(size_t)(gmb + r) * H + colg] = f2b(acc[mt][nt + 4][r] + bb);
                }
            }
        }
    }
}

// ---- fused layer-3: agg128 + gemv (register-resident h2) -----------------
__global__ __launch_bounds__(256) void agg_gemv3(
    const int* __restrict__ endoff, const int* __restrict__ csr,
    const unsigned short* __restrict__ T, const unsigned short* __restrict__ Ab,
    const float* __restrict__ Wl, const float* __restrict__ Wr,
    const float* __restrict__ b,
    float* __restrict__ t3, float* __restrict__ out, int N)
{
    const int node = (int)((blockIdx.x * 256 + threadIdx.x) >> 5);
    const int lane = threadIdx.x & 31;
    if (node >= N) return;
    const int end = endoff[node];
    const int beg = node ? endoff[node - 1] : 0;
    float s0 = 0.f, s1 = 0.f, s2 = 0.f, s3 = 0.f;
    int p = beg;
    for (; p + 4 <= end; p += 4) {
        const int a = csr[p], bb = csr[p + 1], c = csr[p + 2], d = csr[p + 3];
        ushort4 v0 = *(const ushort4*)(T + ((size_t)a << 7) + (lane << 2));
        ushort4 v1 = *(const ushort4*)(T + ((size_t)bb << 7) + (lane << 2));
        ushort4 v2 = *(const ushort4*)(T + ((size_t)c << 7) + (lane << 2));
        ushort4 v3 = *(const ushort4*)(T + ((size_t)d << 7) + (lane << 2));
        s0 += (b2f(v0.x) + b2f(v1.x)) + (b2f(v2.x) + b2f(v3.x));
        s1 += (b2f(v0.y) + b2f(v1.y)) + (b2f(v2.y) + b2f(v3.y));
        s2 += (b2f(v0.z) + b2f(v1.z)) + (b2f(v2.z) + b2f(v3.z));
        s3 += (b2f(v0.w) + b2f(v1.w)) + (b2f(v2.w) + b2f(v3.w));
    }
    for (; p < end; ++p) {
        ushort4 v = *(const ushort4*)(T + ((size_t)csr[p] << 7) + (lane << 2));
        s0 += b2f(v.x); s1 += b2f(v.y); s2 += b2f(v.z); s3 += b2f(v.w);
    }
    const float w = 1.0f / fmaxf((float)(end - beg), 1.0f);
    const ushort4 bu = *(const ushort4*)(Ab + ((size_t)node << 7) + (lane << 2));
    const float h0 = fmaxf(b2f(bu.x) + s0 * w, 0.f);
    const float h1 = fmaxf(b2f(bu.y) + s1 * w, 0.f);
    const float h2 = fmaxf(b2f(bu.z) + s2 * w, 0.f);
    const float h3 = fmaxf(b2f(bu.w) + s3 * w, 0.f);

    const float4 wl = *(const float4*)(Wl + (lane << 2));
    const float4 wr = *(const float4*)(Wr + (lane << 2));
    float dl = h0 * wl.x + h1 * wl.y + h2 * wl.z + h3 * wl.w;
    float dr = h0 * wr.x + h1 * wr.y + h2 * wr.z + h3 * wr.w;
    #pragma unroll
    for (int off = 16; off > 0; off >>= 1) {
        dl += __shfl_down(dl, off, 64);
        dr += __shfl_down(dr, off, 64);
    }
    if (lane == 0) {
        t3[node] = dl;
        out[node] = dr + b[0];
    }
}

__global__ __launch_bounds__(256) void agg1(
    const int* __restrict__ endoff, const int* __restrict__ csr,
    const float* __restrict__ t3, float* __restrict__ out, int N)
{
    const int i = blockIdx.x * blockDim.x + threadIdx.x;
    if (i >= N) return;
    const int end = endoff[i];
    const int beg = i ? endoff[i - 1] : 0;
    int p = beg;
    float s = 0.f;
    for (; p + 4 <= end; p += 4)
        s += (t3[csr[p]] + t3[csr[p + 1]]) + (t3[csr[p + 2]] + t3[csr[p + 3]]);
    for (; p < end; ++p) s += t3[csr[p]];
    out[i] += s / fmaxf((float)(end - beg), 1.0f);
}

extern "C" void kernel_launch(void* const* d_in, const int* in_sizes, int n_in,
                              void* d_out, int out_size, void* d_ws, size_t ws_size,
                              hipStream_t stream) {
    const float* x   = (const float*)d_in[0];
    const int*   ei  = (const int*)d_in[1];
    const float* Wl1 = (const float*)d_in[2];
    const float* bl1 = (const float*)d_in[3];
    const float* Wr1 = (const float*)d_in[4];
    const float* Wl2 = (const float*)d_in[5];
    const float* bl2 = (const float*)d_in[6];
    const float* Wr2 = (const float*)d_in[7];
    const float* Wl3 = (const float*)d_in[8];
    const float* bl3 = (const float*)d_in[9];
    const float* Wr3 = (const float*)d_in[10];
    float* out = (float*)d_out;

    const int N = in_sizes[0] / 256;   // 100000
    const int E = in_sizes[1] / 2;     // 1600000
    const int* src = ei;
    const int* dst = ei + E;

    // ---- workspace layout, race-free aliasing ----------------------------
    //   prep:       W X1b[0,51.2)
    //   L1+fill:    R X1b              W T1b[51.2,102.4) A1b[102.4,153.6) csr
    //   agg256_b:   R T1b,A1b,csr      W X2b[0,51.2)        (X1b dead)
    //   gemm_l2:    R X2b              W T2b[51.2,76.8) A2b[76.8,102.4)
    //                                                       (T1b/A1b dead)
    //   agg_gemv3:  R T2b,A2b,csr      W t3,out             (X2b dead)
    //   agg1:       R t3,csr           RW out
    char* W = (char*)d_ws;
    const size_t MB512 = (size_t)100000 * 512;   // 51.2MB
    unsigned short* X1b = (unsigned short*)(W);
    unsigned short* T1b = (unsigned short*)(W + MB512);
    unsigned short* A1b = (unsigned short*)(W + 2 * MB512);
    unsigned short* X2b = (unsigned short*)(W);                  // over dead X1b
    unsigned short* T2b = (unsigned short*)(W + MB512);          // over dead T1b
    unsigned short* A2b = (unsigned short*)(W + MB512 + MB512 / 2);
    char* S = W + 3 * MB512;                     // smalls @ 153.6M
    int*   endoff = (int*)(S);
    int*   bsums  = (int*)(S + (size_t)N * 4);
    float* t3     = (float*)(S + (size_t)N * 4 + 1024);
    int*   csr    = (int*)(S + (size_t)N * 8 + 1024);
    unsigned short* Wl1s = (unsigned short*)(S + (size_t)N * 8 + 1024 + (size_t)E * 4);
    unsigned short* Wr1s = Wl1s + 65536;
    unsigned short* Wl2s = Wr1s + 65536;
    unsigned short* Wr2s = Wl2s + 32768;

    // ---- prep: fused conversions + degree count ----
    hipMemsetAsync(endoff, 0, (size_t)N * sizeof(int), stream);
    prep_fused<<<32018, 256, 0, stream>>>(x, X1b, Wl1, Wr1, Wl2, Wr2,
                                          Wl1s, Wr1s, Wl2s, Wr2s,
                                          dst, endoff, E);
    const int nScanBlocks = (N + 1023) / 1024;
    scan_phaseA<<<nScanBlocks, 256, 0, stream>>>(endoff, bsums, N);
    scan_phaseB<<<1, 256, 0, stream>>>(bsums, nScanBlocks);
    scan_phaseC<<<nScanBlocks, 256, 0, stream>>>(endoff, bsums, N);

    // ---- Layer 1 GEMM fused with fill_csr ----
    gemm_l1_fill<<<3128 * 3, 256, 0, stream>>>(X1b, Wl1s, Wr1s, bl1, T1b, A1b, N,
                                               src, dst, endoff, csr, E);

    // ---- Layer 2: gather (half-wave/node) then GEMM ----
    agg256_b<<<(N * 32 + 255) / 256, 256, 0, stream>>>(endoff, csr, T1b, A1b, X2b, N);
    gemm_bf16<<<dim3(2, (N + 127) / 128), 256, 0, stream>>>(X2b, Wl2s, Wr2s, bl2,
                                                            T2b, A2b, N, 128);

    // ---- Layer 3: fused agg128 + gemv, then final scalar aggregation ----
    agg_gemv3<<<(N * 32 + 255) / 256, 256, 0, stream>>>(endoff, csr, T2b, A2b,
                                                        Wl3, Wr3, bl3, t3, out, N);
    agg1<<<(N + 255) / 256, 256, 0, stream>>>(endoff, csr, t3, out, N);
}